// Round 2
// baseline (1568.500 us; speedup 1.0000x reference)
//
#include <hip/hip_runtime.h>
#include <hip/hip_bf16.h>

// ARMANet: 2x ARMAConv(K=1,T=1) + global mean pool + FC
// N=100000 nodes, E=1600000 edges, IN=HID=64, OUT=32, G=64 graphs.
// R21: push-style gather with lockstep source sweep.
//  - bucket_kernel (+fused wprep) unchanged: 2048-edge chunks -> dest buckets.
//  - sort_kernel (was csr): counting sort per bucket by SOURCE CHUNK (src>>9),
//    es = packed (dlo<<24)|src words; dest histogram -> dinv only (no CSR).
//  - push_gather: block = 256-dest bucket, f32 LDS acc[256][67] (68.6 KB,
//    2 blocks/CU, grid fully co-resident). Streams source-sorted edges ->
//    all blocks sweep Ts in ascending source order ~in lockstep -> per-XCD
//    L2 holds the moving window -> FETCH drops vs random pull (162 MB).
//    ds_add_f32 accumulate, fused relu(dinv*acc+Rs) epilogue (uint4 I/O).
//  - NT es load reverted (R20: regressed gather 52.7->55.0 us).
//  - MFMA dual GEMM / pool / fc unchanged.

#define NB 256
#define CAP 5120
#define MAXB 400
#define P1_CHUNK 2048
#define ACC_STRIDE 67

typedef unsigned int uint32;
typedef unsigned short ushort16;
typedef __attribute__((ext_vector_type(8))) short short8;   // 8 bf16 (4 VGPRs)
typedef __attribute__((ext_vector_type(4))) float f32x4;    // MFMA C/D

__device__ inline uint32 bf16rn(float f) {
    uint32 u = __float_as_uint(f);
    uint32 r = ((u >> 16) & 1u) + 0x7FFFu;
    return (u + r) >> 16;
}
__device__ inline uint32 pack_bf16(float a, float b) {
    return bf16rn(a) | (bf16rn(b) << 16);
}
__device__ inline float bflo(uint32 u) { return __uint_as_float(u << 16); }
__device__ inline float bfhi(uint32 u) { return __uint_as_float(u & 0xFFFF0000u); }

// ---------------- stage 1: bucket edges by destination (+ fused weight prep) ----------------
// blocks [0,128): weights -> transposed split-bf16 table wt[m][d*64+k]
//   m: 0=init_hi 1=init_lo 2=root_hi 3=root_lo (x2 layers -> 8 mats).
// blocks [128,...): 2048-edge chunk bucketing by col>>8.
__global__ __launch_bounds__(256) void bucket_kernel(
    const int* __restrict__ row, const int* __restrict__ col,
    uint32* __restrict__ bpack, int* __restrict__ bcnt, int E,
    const float* __restrict__ W1i, const float* __restrict__ W1r,
    const float* __restrict__ W2i, const float* __restrict__ W2r,
    ushort16* __restrict__ wt) {
    __shared__ int hist[MAXB];
    __shared__ int ofs[MAXB];
    __shared__ int cur[MAXB];
    __shared__ int gbase[MAXB];
    __shared__ int s[256];
    __shared__ uint32 stage[P1_CHUNK];
    __shared__ unsigned short stage_bk[P1_CHUNK];

    int t = threadIdx.x;

    if (blockIdx.x < 128) {
        // ---- wprep role ----
        int idx = blockIdx.x * 256 + t;     // 8*4096 items over 128 blocks
        int m = idx >> 12;
        int r = idx & 4095;
        int d = r >> 6, k = r & 63;
        const float* W = (m < 2) ? W1i : (m < 4) ? W1r : (m < 6) ? W2i : W2r;
        float v = W[k * 64 + d];
        uint32 hi = bf16rn(v);
        uint32 outv;
        if (m & 1) {
            float hf = __uint_as_float(hi << 16);
            outv = bf16rn(v - hf);
        } else {
            outv = hi;
        }
        wt[(size_t)m * 4096 + d * 64 + k] = (unsigned short)outv;
        return;
    }

    for (int i = t; i < MAXB; i += 256) hist[i] = 0;
    __syncthreads();

    int e0 = (blockIdx.x - 128) * P1_CHUNK;
    int cntE = min(E - e0, P1_CHUNK);

    for (int i = t; i < cntE; i += 256) {
        int c = col[e0 + i];
        atomicAdd(&hist[c >> 8], 1);
    }
    __syncthreads();

    int i2 = 2 * t;
    int a = (i2 < MAXB) ? hist[i2] : 0;
    int b = (i2 + 1 < MAXB) ? hist[i2 + 1] : 0;
    s[t] = a + b;
    __syncthreads();
    for (int off = 1; off < 256; off <<= 1) {
        int x = (t >= off) ? s[t - off] : 0;
        __syncthreads();
        s[t] += x;
        __syncthreads();
    }
    int excl = (t > 0) ? s[t - 1] : 0;
    if (i2 < MAXB) ofs[i2] = excl;
    if (i2 + 1 < MAXB) ofs[i2 + 1] = excl + a;
    __syncthreads();

    for (int i = t; i < MAXB; i += 256) {
        cur[i] = ofs[i];
        gbase[i] = hist[i] ? atomicAdd(&bcnt[i], hist[i]) : 0;
    }
    __syncthreads();

    for (int i = t; i < cntE; i += 256) {
        int c = col[e0 + i];
        int r = row[e0 + i];
        int bk = c >> 8;
        int k = atomicAdd(&cur[bk], 1);
        stage[k] = ((uint32)(c & 255) << 24) | (uint32)r;
        stage_bk[k] = (unsigned short)bk;
    }
    __syncthreads();

    for (int i = t; i < cntE; i += 256) {
        uint32 pk = stage[i];
        int bk = stage_bk[i];
        int gd = gbase[bk] + (i - ofs[bk]);
        if (gd < CAP) bpack[(size_t)bk * CAP + gd] = pk;
    }
}

// ---------------- stage 2: per-bucket counting sort by SOURCE chunk + dinv ----------------
// es[base+p] = packed (dlo<<24)|src, sorted by src>>9 (512-node chunks) so the
// push gather sweeps Ts in ascending source order. Dest histogram -> dinv.
__global__ __launch_bounds__(1024) void sort_kernel(
    const uint32* __restrict__ bpack, const int* __restrict__ bcnt,
    uint32* __restrict__ es, float* __restrict__ dinv, int n) {
    __shared__ uint32 sbp[CAP];   // 20 KB
    __shared__ int hs[NB];        // source-chunk histogram (sort key)
    __shared__ int hd[NB];        // dest-lo histogram (degree)
    __shared__ int s[NB];
    __shared__ int cur[NB];
    int b = blockIdx.x, t = threadIdx.x;
    if (t < NB) { hs[t] = 0; hd[t] = 0; }
    __syncthreads();
    int cnt = min(bcnt[b], CAP);
    size_t base = (size_t)b * CAP;
    for (int i = t; i < cnt; i += 1024) {
        uint32 pk = bpack[base + i];
        sbp[i] = pk;
        atomicAdd(&hs[(pk & 0xFFFFFFu) >> 9], 1);
        atomicAdd(&hd[pk >> 24], 1);
    }
    __syncthreads();
    if (t < NB) s[t] = hs[t];
    __syncthreads();
    for (int off = 1; off < NB; off <<= 1) {
        int x = 0;
        if (t < NB && t >= off) x = s[t - off];
        __syncthreads();
        if (t < NB) s[t] += x;
        __syncthreads();
    }
    if (t < NB) {
        cur[t] = s[t] - hs[t];
        int node = b * NB + t;
        if (node < n) dinv[node] = hd[t] ? rsqrtf((float)hd[t]) : 0.0f;
    }
    __syncthreads();
    for (int i = t; i < cnt; i += 1024) {
        uint32 pk = sbp[i];
        int cl = (int)((pk & 0xFFFFFFu) >> 9);
        int p = atomicAdd(&cur[cl], 1);
        es[base + p] = pk;
    }
}

// ---------------- MFMA dual GEMM (fused f32->bf16 X staging) ----------------
// Ts = bf16(dinv .* (X@Winit)), Rs = bf16(X@Wroot + bias).
// X: f32 (xf32=1, layer 1) or packed bf16 uint rows (xf32=0, layer 2).
// Swapped MFMA operands -> transposed C tile: each thread holds 4 consecutive
// dims of ONE node -> packed uint2 stores, coalesced per-node dinv loads.
__global__ __launch_bounds__(256) void gemm_mfma(
    const void* __restrict__ Xin,
    const ushort16* __restrict__ wt4,         // 4 mats: init_hi, init_lo, root_hi, root_lo
    const float* __restrict__ bias, const float* __restrict__ dinv,
    ushort16* __restrict__ Ts, ushort16* __restrict__ Rs, int n, int xf32) {
    __shared__ unsigned short sXs[64 * 72];   // 9216 B, row stride 72 bf16
    int t = threadIdx.x;
    int node0 = blockIdx.x * 64;

    if (xf32) {
        const float* X = (const float*)Xin;
        for (int i = t; i < 1024; i += 256) {
            int r = i >> 4, c4 = (i & 15) * 4;
            int node = node0 + r;
            float4 v = make_float4(0.f, 0.f, 0.f, 0.f);
            if (node < n) v = *(const float4*)&X[(size_t)node * 64 + c4];
            *(uint32*)&sXs[r * 72 + c4] = pack_bf16(v.x, v.y);
            *(uint32*)&sXs[r * 72 + c4 + 2] = pack_bf16(v.z, v.w);
        }
    } else {
        const uint32* Xb2 = (const uint32*)Xin;
        for (int i = t; i < 512; i += 256) {
            int r = i >> 3, kg = i & 7;
            int node = node0 + r;
            uint4 v = make_uint4(0u, 0u, 0u, 0u);
            if (node < n) v = *(const uint4*)&Xb2[(size_t)node * 32 + kg * 4];
            *(uint4*)&sXs[r * 72 + kg * 8] = v;
        }
    }

    int w = t >> 6;
    int lane = t & 63;
    int q = lane >> 4;
    int col = lane & 15;
    int dim = w * 16 + col;   // output dim carried by lane&15

    // B fragments from precomputed table (16 B loads, L2-hot)
    short8 bih[2], bil[2], brh[2], brl[2];
#pragma unroll
    for (int kh = 0; kh < 2; ++kh) {
        size_t o = (size_t)dim * 64 + kh * 32 + q * 8;
        bih[kh] = *(const short8*)&wt4[0 * 4096 + o];
        bil[kh] = *(const short8*)&wt4[1 * 4096 + o];
        brh[kh] = *(const short8*)&wt4[2 * 4096 + o];
        brl[kh] = *(const short8*)&wt4[3 * 4096 + o];
    }
    float4 bias4 = *(const float4*)&bias[w * 16 + q * 4];
    __syncthreads();

    unsigned short* TsU = (unsigned short*)Ts;
    unsigned short* RsU = (unsigned short*)Rs;

#pragma unroll
    for (int mt = 0; mt < 4; ++mt) {
        int rbase = mt * 16 + col;
        short8 a0 = *(const short8*)&sXs[rbase * 72 + q * 8];
        short8 a1 = *(const short8*)&sXs[rbase * 72 + 32 + q * 8];
        f32x4 accT = {0.f, 0.f, 0.f, 0.f};
        f32x4 accR = {0.f, 0.f, 0.f, 0.f};
        // swapped operands: D = W^T * X^T = (X @ W)^T
        accT = __builtin_amdgcn_mfma_f32_16x16x32_bf16(bih[0], a0, accT, 0, 0, 0);
        accT = __builtin_amdgcn_mfma_f32_16x16x32_bf16(bih[1], a1, accT, 0, 0, 0);
        accT = __builtin_amdgcn_mfma_f32_16x16x32_bf16(bil[0], a0, accT, 0, 0, 0);
        accT = __builtin_amdgcn_mfma_f32_16x16x32_bf16(bil[1], a1, accT, 0, 0, 0);
        accR = __builtin_amdgcn_mfma_f32_16x16x32_bf16(brh[0], a0, accR, 0, 0, 0);
        accR = __builtin_amdgcn_mfma_f32_16x16x32_bf16(brh[1], a1, accR, 0, 0, 0);
        accR = __builtin_amdgcn_mfma_f32_16x16x32_bf16(brl[0], a0, accR, 0, 0, 0);
        accR = __builtin_amdgcn_mfma_f32_16x16x32_bf16(brl[1], a1, accR, 0, 0, 0);

        int node = node0 + mt * 16 + col;
        if (node < n) {
            float dv = dinv[node];
            uint2 pT, pR;
            pT.x = pack_bf16(accT[0] * dv, accT[1] * dv);
            pT.y = pack_bf16(accT[2] * dv, accT[3] * dv);
            pR.x = pack_bf16(accR[0] + bias4.x, accR[1] + bias4.y);
            pR.y = pack_bf16(accR[2] + bias4.z, accR[3] + bias4.w);
            size_t o = (size_t)node * 64 + w * 16 + q * 4;
            *(uint2*)&TsU[o] = pT;
            *(uint2*)&RsU[o] = pR;
        }
    }
}

// ---------------- push gather: source-sweep accumulate into LDS, fused relu ----------------
// Block = one 256-dest bucket. acc[256][67] f32 (68.6 KB -> 2 blocks/CU, all
// 391 blocks co-resident). Edges sorted by src chunk -> all blocks read Ts in
// ascending source order ~in lockstep -> per-XCD L2 captures the moving window.
// Quarter q handles edge j+q: 16 lanes load the 128-B Ts row (uint2 each),
// unpack and ds_add_f32 into acc[dlo]. Epilogue: h = relu(dinv*acc + Rs).
__global__ __launch_bounds__(1024) void push_gather(
    const uint2* __restrict__ Ts2, const uint2* __restrict__ Rs2,
    const uint32* __restrict__ es, const int* __restrict__ bcnt,
    const float* __restrict__ dinv, uint2* __restrict__ Hb2, int n) {
    __shared__ float acc[NB * ACC_STRIDE];   // 68608 B
    int b = blockIdx.x, t = threadIdx.x;
    for (int i = t; i < NB * ACC_STRIDE; i += 1024) acc[i] = 0.0f;
    __syncthreads();

    int cnt = min(bcnt[b], CAP);
    size_t base = (size_t)b * CAP;
    int lane = t & 63;
    int q = lane >> 4;    // edge slot 0..3
    int d4 = lane & 15;   // dim quad
    int wave = t >> 6;    // 16 waves

    for (int i0 = wave * 64; i0 < cnt; i0 += 1024) {
        int m = min(cnt - i0, 64);
        uint32 ew = (lane < m) ? es[base + i0 + lane] : 0u;
        for (int j = 0; j < m; j += 4) {
            int e = j + q;
            uint32 w = __shfl(ew, e);
            if (e < m) {
                int src = (int)(w & 0xFFFFFFu);
                int dlo = (int)(w >> 24);
                uint2 v = Ts2[(size_t)src * 16 + d4];
                float* ap = &acc[dlo * ACC_STRIDE + d4 * 4];
                atomicAdd(ap + 0, bflo(v.x));
                atomicAdd(ap + 1, bfhi(v.x));
                atomicAdd(ap + 2, bflo(v.y));
                atomicAdd(ap + 3, bfhi(v.y));
            }
        }
    }
    __syncthreads();

    // epilogue: 4 threads per dest row, 16 dims each; coalesced uint4 I/O
    int r = t >> 2;
    int node = b * NB + r;
    if (node < n) {
        float dc = dinv[node];
        int cg = (t & 3) * 16;
        const uint4* rsp = (const uint4*)&Rs2[(size_t)node * 16];
        uint4 ua = rsp[(t & 3) * 2];
        uint4 ub = rsp[(t & 3) * 2 + 1];
        const float* ac = &acc[r * ACC_STRIDE + cg];
        uint4 o0, o1;
        o0.x = pack_bf16(fmaxf(fmaf(dc, ac[0],  bflo(ua.x)), 0.f), fmaxf(fmaf(dc, ac[1],  bfhi(ua.x)), 0.f));
        o0.y = pack_bf16(fmaxf(fmaf(dc, ac[2],  bflo(ua.y)), 0.f), fmaxf(fmaf(dc, ac[3],  bfhi(ua.y)), 0.f));
        o0.z = pack_bf16(fmaxf(fmaf(dc, ac[4],  bflo(ua.z)), 0.f), fmaxf(fmaf(dc, ac[5],  bfhi(ua.z)), 0.f));
        o0.w = pack_bf16(fmaxf(fmaf(dc, ac[6],  bflo(ua.w)), 0.f), fmaxf(fmaf(dc, ac[7],  bfhi(ua.w)), 0.f));
        o1.x = pack_bf16(fmaxf(fmaf(dc, ac[8],  bflo(ub.x)), 0.f), fmaxf(fmaf(dc, ac[9],  bfhi(ub.x)), 0.f));
        o1.y = pack_bf16(fmaxf(fmaf(dc, ac[10], bflo(ub.y)), 0.f), fmaxf(fmaf(dc, ac[11], bfhi(ub.y)), 0.f));
        o1.z = pack_bf16(fmaxf(fmaf(dc, ac[12], bflo(ub.z)), 0.f), fmaxf(fmaf(dc, ac[13], bfhi(ub.z)), 0.f));
        o1.w = pack_bf16(fmaxf(fmaf(dc, ac[14], bflo(ub.w)), 0.f), fmaxf(fmaf(dc, ac[15], bfhi(ub.w)), 0.f));
        uint4* hp = (uint4*)&Hb2[(size_t)node * 16];
        hp[(t & 3) * 2] = o0;
        hp[(t & 3) * 2 + 1] = o1;
    }
}

// ---------------- mean-pool over sorted batch (bf16x2 loads, half-wave/node) ----------------
__global__ __launch_bounds__(256) void pool_kernel(
    const uint32* __restrict__ Hb, const int* __restrict__ batch,
    float* __restrict__ pooled, float* __restrict__ cnt, int n) {
    __shared__ float sAcc[64 * 64];
    __shared__ float sCnt[64];
    int tid = threadIdx.x;
    for (int i = tid; i < 4096; i += 256) sAcc[i] = 0.0f;
    if (tid < 64) sCnt[tid] = 0.0f;
    __syncthreads();

    int w = tid >> 6, lane = tid & 63;
    int half = lane >> 5, d2 = lane & 31;
    int s = blockIdx.x * 256 + w * 64;
    int e = min(s + 64, n);
    float a0 = 0.0f, a1 = 0.0f, c = 0.0f;
    int gcur = -1;
    for (int i = s + half; i < e; i += 2) {
        int g = batch[i];
        if (g != gcur) {
            if (gcur >= 0) {
                atomicAdd(&sAcc[gcur * 64 + 2 * d2], a0);
                atomicAdd(&sAcc[gcur * 64 + 2 * d2 + 1], a1);
                if (d2 == 0) atomicAdd(&sCnt[gcur], c);
            }
            gcur = g; a0 = 0.0f; a1 = 0.0f; c = 0.0f;
        }
        uint32 u = Hb[(size_t)i * 32 + d2];
        a0 += bflo(u);
        a1 += bfhi(u);
        c += 1.0f;
    }
    if (gcur >= 0) {
        atomicAdd(&sAcc[gcur * 64 + 2 * d2], a0);
        atomicAdd(&sAcc[gcur * 64 + 2 * d2 + 1], a1);
        if (d2 == 0) atomicAdd(&sCnt[gcur], c);
    }
    __syncthreads();
    for (int i = tid; i < 4096; i += 256) {
        float v = sAcc[i];
        if (v != 0.0f) atomicAdd(&pooled[i], v);
    }
    if (tid < 64) {
        float v = sCnt[tid];
        if (v != 0.0f) atomicAdd(&cnt[tid], v);
    }
}

// ---------------- out[g,o] = (pooled[g,:]/max(cnt,1)) @ fcw + fcb ----------------
__global__ void final_fc(const float* __restrict__ pooled, const float* __restrict__ cnt,
                         const float* __restrict__ fcw, const float* __restrict__ fcb,
                         float* __restrict__ out) {
    int idx = blockIdx.x * 256 + threadIdx.x;
    if (idx >= 64 * 32) return;
    int g = idx >> 5, o = idx & 31;
    float c = fmaxf(cnt[g], 1.0f);
    float acc = 0.0f;
#pragma unroll
    for (int k = 0; k < 64; ++k) acc = fmaf(pooled[g * 64 + k], fcw[k * 32 + o], acc);
    out[idx] = acc / c + fcb[o];
}

extern "C" void kernel_launch(void* const* d_in, const int* in_sizes, int n_in,
                              void* d_out, int out_size, void* d_ws, size_t ws_size,
                              hipStream_t stream) {
    const float* x       = (const float*)d_in[0];
    const int*   eidx    = (const int*)d_in[1];
    const int*   batch   = (const int*)d_in[2];
    const float* w1_init = (const float*)d_in[3];
    const float* w1_root = (const float*)d_in[4];
    const float* b1      = (const float*)d_in[5];
    const float* w2_init = (const float*)d_in[6];
    const float* w2_root = (const float*)d_in[7];
    const float* b2      = (const float*)d_in[8];
    const float* fc_w    = (const float*)d_in[9];
    const float* fc_b    = (const float*)d_in[10];
    float* out = (float*)d_out;

    const int N = in_sizes[0] / 64;
    const int E = in_sizes[1] / 2;
    const int* row = eidx;
    const int* col = eidx + E;

    const int B = (N + NB - 1) / NB;  // 391 buckets

    // workspace (4-byte units, 16B-aligned chunks):
    // bpack(B*CAP) | es(B*CAP) | bcnt(MAXB) | pooled(4096) | cnt(64)
    // | dinv(N) | wt(16384 uints = 8 mats * 4096 ushorts) | Ts(N*32) | Rs(N*32) | Hb(N*32)
    uint32* bpack = (uint32*)d_ws;
    uint32* es    = bpack + (size_t)B * CAP;
    int*   bcnt   = (int*)(es + (size_t)B * CAP);
    float* pooled = (float*)(bcnt + MAXB);
    float* cnt    = pooled + 64 * 64;
    float* dinv   = cnt + 64;
    uint32* wtU   = (uint32*)(dinv + N);            // 16384 uints (64 KB)
    uint32* Ts    = wtU + 16384;                    // N*32
    uint32* Rs    = Ts + (size_t)N * 32;            // N*32
    uint32* Hb    = Rs + (size_t)N * 32;            // N*32
    ushort16* wt  = (ushort16*)wtU;

    hipMemsetAsync(bcnt, 0, (size_t)(MAXB + 64 * 64 + 64) * sizeof(int), stream);

    // bucket + fused weight prep (first 128 blocks), then source-chunk sort
    const int EB = (E + P1_CHUNK - 1) / P1_CHUNK;
    bucket_kernel<<<128 + EB, 256, 0, stream>>>(row, col, bpack, bcnt, E,
                                                w1_init, w1_root, w2_init, w2_root, wt);
    sort_kernel<<<B, 1024, 0, stream>>>(bpack, bcnt, es, dinv, N);

    // layer 1 (f32 input); wt = mats 0..3 (layer-1 init_hi/init_lo/root_hi/root_lo)
    gemm_mfma<<<(N + 63) / 64, 256, 0, stream>>>(x, wt, b1, dinv,
                                                 (ushort16*)Ts, (ushort16*)Rs, N, 1);
    push_gather<<<B, 1024, 0, stream>>>((const uint2*)Ts, (const uint2*)Rs,
                                        es, bcnt, dinv, (uint2*)Hb, N);

    // layer 2 (bf16 input); wt + 4*4096 ushorts = mats 4..7 (layer-2 weights)
    gemm_mfma<<<(N + 63) / 64, 256, 0, stream>>>(Hb, wt + (size_t)4 * 4096, b2, dinv,
                                                 (ushort16*)Ts, (ushort16*)Rs, N, 0);
    push_gather<<<B, 1024, 0, stream>>>((const uint2*)Ts, (const uint2*)Rs,
                                        es, bcnt, dinv, (uint2*)Hb, N);

    // pool + FC
    pool_kernel<<<(N + 255) / 256, 256, 0, stream>>>(Hb, batch, pooled, cnt, N);
    final_fc<<<(64 * 32 + 255) / 256, 256, 0, stream>>>(pooled, cnt, fc_w, fc_b, out);
}

// Round 3
// 398.898 us; speedup vs baseline: 3.9321x; 3.9321x over previous
//
#include <hip/hip_runtime.h>
#include <hip/hip_bf16.h>

// ARMANet: 2x ARMAConv(K=1,T=1) + global mean pool + FC
// N=100000 nodes, E=1600000 edges, IN=HID=64, OUT=32, G=64 graphs.
// R22: push gather v2 -- register accumulators, zero atomics.
//  R21 post-mortem: source-sweep DID cut FETCH 162->100 MB (= 8 XCD x 12.8 MB
//  window floor), but LDS f32 atomics serialized (200k bank conflicts, 697us).
//  v2 keeps the sweep, moves accumulation to registers:
//  - sort key = (owner_wave major, src_chunk minor), owner = dlo>>4: each of
//    16 waves owns 16 dests; its edges are ONE contiguous source-sorted run.
//  - push_gather: block = 256-dest bucket, 1024 thr. Wave sweeps its run,
//    4 edges/round (16 lanes x uint2 per row), shfl-redistributes dim l to
//    lane l, scalarized 4-deep branch tree -> 16 static f32 acc regs.
//    Double-buffered rounds for MLP. All 391 blocks co-resident -> lockstep.
//  - epilogue: h = relu(dinv*acc + Rs), 2B/lane coalesced row writes.
//  - bucket(+wprep), gemm, pool, fc unchanged.

#define NB 256
#define CAP 5120
#define MAXB 400
#define P1_CHUNK 2048
#define KCH 196                 // src chunks: ceil(100000/512)
#define NKEY (16 * KCH)         // 3136 sort keys

typedef unsigned int uint32;
typedef unsigned short ushort16;
typedef __attribute__((ext_vector_type(8))) short short8;   // 8 bf16 (4 VGPRs)
typedef __attribute__((ext_vector_type(4))) float f32x4;    // MFMA C/D

__device__ inline uint32 bf16rn(float f) {
    uint32 u = __float_as_uint(f);
    uint32 r = ((u >> 16) & 1u) + 0x7FFFu;
    return (u + r) >> 16;
}
__device__ inline uint32 pack_bf16(float a, float b) {
    return bf16rn(a) | (bf16rn(b) << 16);
}
__device__ inline float bflo(uint32 u) { return __uint_as_float(u << 16); }
__device__ inline float bfhi(uint32 u) { return __uint_as_float(u & 0xFFFF0000u); }

// ---------------- stage 1: bucket edges by destination (+ fused weight prep) ----------------
__global__ __launch_bounds__(256) void bucket_kernel(
    const int* __restrict__ row, const int* __restrict__ col,
    uint32* __restrict__ bpack, int* __restrict__ bcnt, int E,
    const float* __restrict__ W1i, const float* __restrict__ W1r,
    const float* __restrict__ W2i, const float* __restrict__ W2r,
    ushort16* __restrict__ wt) {
    __shared__ int hist[MAXB];
    __shared__ int ofs[MAXB];
    __shared__ int cur[MAXB];
    __shared__ int gbase[MAXB];
    __shared__ int s[256];
    __shared__ uint32 stage[P1_CHUNK];
    __shared__ unsigned short stage_bk[P1_CHUNK];

    int t = threadIdx.x;

    if (blockIdx.x < 128) {
        // ---- wprep role ----
        int idx = blockIdx.x * 256 + t;     // 8*4096 items over 128 blocks
        int m = idx >> 12;
        int r = idx & 4095;
        int d = r >> 6, k = r & 63;
        const float* W = (m < 2) ? W1i : (m < 4) ? W1r : (m < 6) ? W2i : W2r;
        float v = W[k * 64 + d];
        uint32 hi = bf16rn(v);
        uint32 outv;
        if (m & 1) {
            float hf = __uint_as_float(hi << 16);
            outv = bf16rn(v - hf);
        } else {
            outv = hi;
        }
        wt[(size_t)m * 4096 + d * 64 + k] = (unsigned short)outv;
        return;
    }

    for (int i = t; i < MAXB; i += 256) hist[i] = 0;
    __syncthreads();

    int e0 = (blockIdx.x - 128) * P1_CHUNK;
    int cntE = min(E - e0, P1_CHUNK);

    for (int i = t; i < cntE; i += 256) {
        int c = col[e0 + i];
        atomicAdd(&hist[c >> 8], 1);
    }
    __syncthreads();

    int i2 = 2 * t;
    int a = (i2 < MAXB) ? hist[i2] : 0;
    int b = (i2 + 1 < MAXB) ? hist[i2 + 1] : 0;
    s[t] = a + b;
    __syncthreads();
    for (int off = 1; off < 256; off <<= 1) {
        int x = (t >= off) ? s[t - off] : 0;
        __syncthreads();
        s[t] += x;
        __syncthreads();
    }
    int excl = (t > 0) ? s[t - 1] : 0;
    if (i2 < MAXB) ofs[i2] = excl;
    if (i2 + 1 < MAXB) ofs[i2 + 1] = excl + a;
    __syncthreads();

    for (int i = t; i < MAXB; i += 256) {
        cur[i] = ofs[i];
        gbase[i] = hist[i] ? atomicAdd(&bcnt[i], hist[i]) : 0;
    }
    __syncthreads();

    for (int i = t; i < cntE; i += 256) {
        int c = col[e0 + i];
        int r = row[e0 + i];
        int bk = c >> 8;
        int k = atomicAdd(&cur[bk], 1);
        stage[k] = ((uint32)(c & 255) << 24) | (uint32)r;
        stage_bk[k] = (unsigned short)bk;
    }
    __syncthreads();

    for (int i = t; i < cntE; i += 256) {
        uint32 pk = stage[i];
        int bk = stage_bk[i];
        int gd = gbase[bk] + (i - ofs[bk]);
        if (gd < CAP) bpack[(size_t)bk * CAP + gd] = pk;
    }
}

// ---------------- stage 2: counting sort by (owner wave, src chunk) ----------------
// key = (dlo>>4)*KCH + (src>>9). es sorted so each wave's edges are one
// contiguous source-sorted run. obnd[b*17+w] = run starts, [..16] = cnt.
// Dest histogram -> dinv.
__global__ __launch_bounds__(1024) void sort_kernel(
    const uint32* __restrict__ bpack, const int* __restrict__ bcnt,
    uint32* __restrict__ es, int* __restrict__ obnd,
    float* __restrict__ dinv, int n) {
    __shared__ uint32 sbp[CAP];    // 20 KB
    __shared__ int hist[NKEY];     // 12.25 KB
    __shared__ int cur[NKEY];      // 12.25 KB
    __shared__ int s[1024];        // 4 KB
    __shared__ int hd[NB];         // 1 KB
    int b = blockIdx.x, t = threadIdx.x;
    for (int i = t; i < NKEY; i += 1024) hist[i] = 0;
    if (t < NB) hd[t] = 0;
    __syncthreads();
    int cnt = min(bcnt[b], CAP);
    size_t base = (size_t)b * CAP;
    for (int i = t; i < cnt; i += 1024) {
        uint32 pk = bpack[base + i];
        sbp[i] = pk;
        int dlo = (int)(pk >> 24);
        int ch = (int)((pk & 0xFFFFFFu) >> 9);
        atomicAdd(&hist[(dlo >> 4) * KCH + ch], 1);
        atomicAdd(&hd[dlo], 1);
    }
    __syncthreads();
    // block scan over NKEY (4 keys per thread)
    int k0 = t * 4;
    int l0 = (k0 + 0 < NKEY) ? hist[k0 + 0] : 0;
    int l1 = (k0 + 1 < NKEY) ? hist[k0 + 1] : 0;
    int l2 = (k0 + 2 < NKEY) ? hist[k0 + 2] : 0;
    int l3 = (k0 + 3 < NKEY) ? hist[k0 + 3] : 0;
    int mysum = l0 + l1 + l2 + l3;
    s[t] = mysum;
    __syncthreads();
    for (int off = 1; off < 1024; off <<= 1) {
        int x = (t >= off) ? s[t - off] : 0;
        __syncthreads();
        s[t] += x;
        __syncthreads();
    }
    int excl = (t > 0) ? s[t - 1] : 0;
    if (k0 + 0 < NKEY) cur[k0 + 0] = excl;
    if (k0 + 1 < NKEY) cur[k0 + 1] = excl + l0;
    if (k0 + 2 < NKEY) cur[k0 + 2] = excl + l0 + l1;
    if (k0 + 3 < NKEY) cur[k0 + 3] = excl + l0 + l1 + l2;
    if (t < NB) {
        int node = b * NB + t;
        if (node < n) dinv[node] = hd[t] ? rsqrtf((float)hd[t]) : 0.0f;
    }
    __syncthreads();
    // wave run boundaries (before scatter mutates cur)
    if (t < 16) obnd[b * 17 + t] = cur[t * KCH];
    if (t == 16) obnd[b * 17 + 16] = cnt;
    __syncthreads();
    for (int i = t; i < cnt; i += 1024) {
        uint32 pk = sbp[i];
        int dlo = (int)(pk >> 24);
        int ch = (int)((pk & 0xFFFFFFu) >> 9);
        int p = atomicAdd(&cur[(dlo >> 4) * KCH + ch], 1);
        es[base + p] = pk;
    }
}

// ---------------- MFMA dual GEMM (fused f32->bf16 X staging) ----------------
// Ts = bf16(dinv .* (X@Winit)), Rs = bf16(X@Wroot + bias).
__global__ __launch_bounds__(256) void gemm_mfma(
    const void* __restrict__ Xin,
    const ushort16* __restrict__ wt4,
    const float* __restrict__ bias, const float* __restrict__ dinv,
    ushort16* __restrict__ Ts, ushort16* __restrict__ Rs, int n, int xf32) {
    __shared__ unsigned short sXs[64 * 72];   // 9216 B, row stride 72 bf16
    int t = threadIdx.x;
    int node0 = blockIdx.x * 64;

    if (xf32) {
        const float* X = (const float*)Xin;
        for (int i = t; i < 1024; i += 256) {
            int r = i >> 4, c4 = (i & 15) * 4;
            int node = node0 + r;
            float4 v = make_float4(0.f, 0.f, 0.f, 0.f);
            if (node < n) v = *(const float4*)&X[(size_t)node * 64 + c4];
            *(uint32*)&sXs[r * 72 + c4] = pack_bf16(v.x, v.y);
            *(uint32*)&sXs[r * 72 + c4 + 2] = pack_bf16(v.z, v.w);
        }
    } else {
        const uint32* Xb2 = (const uint32*)Xin;
        for (int i = t; i < 512; i += 256) {
            int r = i >> 3, kg = i & 7;
            int node = node0 + r;
            uint4 v = make_uint4(0u, 0u, 0u, 0u);
            if (node < n) v = *(const uint4*)&Xb2[(size_t)node * 32 + kg * 4];
            *(uint4*)&sXs[r * 72 + kg * 8] = v;
        }
    }

    int w = t >> 6;
    int lane = t & 63;
    int q = lane >> 4;
    int col = lane & 15;
    int dim = w * 16 + col;

    short8 bih[2], bil[2], brh[2], brl[2];
#pragma unroll
    for (int kh = 0; kh < 2; ++kh) {
        size_t o = (size_t)dim * 64 + kh * 32 + q * 8;
        bih[kh] = *(const short8*)&wt4[0 * 4096 + o];
        bil[kh] = *(const short8*)&wt4[1 * 4096 + o];
        brh[kh] = *(const short8*)&wt4[2 * 4096 + o];
        brl[kh] = *(const short8*)&wt4[3 * 4096 + o];
    }
    float4 bias4 = *(const float4*)&bias[w * 16 + q * 4];
    __syncthreads();

    unsigned short* TsU = (unsigned short*)Ts;
    unsigned short* RsU = (unsigned short*)Rs;

#pragma unroll
    for (int mt = 0; mt < 4; ++mt) {
        int rbase = mt * 16 + col;
        short8 a0 = *(const short8*)&sXs[rbase * 72 + q * 8];
        short8 a1 = *(const short8*)&sXs[rbase * 72 + 32 + q * 8];
        f32x4 accT = {0.f, 0.f, 0.f, 0.f};
        f32x4 accR = {0.f, 0.f, 0.f, 0.f};
        accT = __builtin_amdgcn_mfma_f32_16x16x32_bf16(bih[0], a0, accT, 0, 0, 0);
        accT = __builtin_amdgcn_mfma_f32_16x16x32_bf16(bih[1], a1, accT, 0, 0, 0);
        accT = __builtin_amdgcn_mfma_f32_16x16x32_bf16(bil[0], a0, accT, 0, 0, 0);
        accT = __builtin_amdgcn_mfma_f32_16x16x32_bf16(bil[1], a1, accT, 0, 0, 0);
        accR = __builtin_amdgcn_mfma_f32_16x16x32_bf16(brh[0], a0, accR, 0, 0, 0);
        accR = __builtin_amdgcn_mfma_f32_16x16x32_bf16(brh[1], a1, accR, 0, 0, 0);
        accR = __builtin_amdgcn_mfma_f32_16x16x32_bf16(brl[0], a0, accR, 0, 0, 0);
        accR = __builtin_amdgcn_mfma_f32_16x16x32_bf16(brl[1], a1, accR, 0, 0, 0);

        int node = node0 + mt * 16 + col;
        if (node < n) {
            float dv = dinv[node];
            uint2 pT, pR;
            pT.x = pack_bf16(accT[0] * dv, accT[1] * dv);
            pT.y = pack_bf16(accT[2] * dv, accT[3] * dv);
            pR.x = pack_bf16(accR[0] + bias4.x, accR[1] + bias4.y);
            pR.y = pack_bf16(accR[2] + bias4.z, accR[3] + bias4.w);
            size_t o = (size_t)node * 64 + w * 16 + q * 4;
            *(uint2*)&TsU[o] = pT;
            *(uint2*)&RsU[o] = pR;
        }
    }
}

// acc-select tree: sd4 is a wave-uniform SGPR -> s_cmp/s_cbranch, static regs
#define ACC_ADD(sd4, val)                                                     \
    if (sd4 < 8) {                                                            \
        if (sd4 < 4) {                                                        \
            if (sd4 < 2) { if (sd4 == 0) a[0] += val; else a[1] += val; }     \
            else         { if (sd4 == 2) a[2] += val; else a[3] += val; }     \
        } else {                                                              \
            if (sd4 < 6) { if (sd4 == 4) a[4] += val; else a[5] += val; }     \
            else         { if (sd4 == 6) a[6] += val; else a[7] += val; }     \
        }                                                                     \
    } else {                                                                  \
        if (sd4 < 12) {                                                       \
            if (sd4 < 10) { if (sd4 == 8)  a[8]  += val; else a[9]  += val; } \
            else          { if (sd4 == 10) a[10] += val; else a[11] += val; } \
        } else {                                                              \
            if (sd4 < 14) { if (sd4 == 12) a[12] += val; else a[13] += val; } \
            else          { if (sd4 == 14) a[14] += val; else a[15] += val; } \
        }                                                                     \
    }

// ---------------- push gather v2: register-accumulating source sweep ----------------
// Block = 256-dest bucket, 16 waves; wave w owns dests [16w,16w+16), its edges
// are es[obnd[w]..obnd[w+1]) sorted by src. 4 edges/round: quarter q's 16
// lanes load the row (uint2); shfl redistributes dim l to lane l; uniform
// branch tree adds into static acc reg. Epilogue: relu(dinv*acc+Rs).
__global__ __launch_bounds__(1024, 8) void push_gather(
    const uint2* __restrict__ Ts2, const unsigned short* __restrict__ RsU,
    const uint32* __restrict__ es, const int* __restrict__ bcnt,
    const int* __restrict__ obnd, const float* __restrict__ dinv,
    unsigned short* __restrict__ HbU, int n) {
    __shared__ uint32 sES[CAP];   // 20 KB
    int b = blockIdx.x, t = threadIdx.x;
    int cnt = min(bcnt[b], CAP);
    size_t base = (size_t)b * CAP;
    for (int i = t; i < cnt; i += 1024) sES[i] = es[base + i];
    __syncthreads();

    int w = t >> 6, lane = t & 63;
    int q = lane >> 4;      // edge slot in round
    int d4l = lane & 15;    // uint2 index within row
    int s0 = obnd[b * 17 + w];
    int e0 = obnd[b * 17 + w + 1];

    float a[16];
#pragma unroll
    for (int j = 0; j < 16; ++j) a[j] = 0.0f;

    // per-lane selectors for redistribution (dim `lane` of a row)
    int rsl = lane >> 2;          // which uint2-holder lane within a quarter
    int selY = lane & 2;
    int selH = lane & 1;

    int nr = (e0 - s0 + 3) >> 2;
    uint32 wd = 0; uint2 v = make_uint2(0u, 0u);
    {
        int idx = s0 + q;
        if (idx < e0) {
            wd = sES[idx];
            v = Ts2[(size_t)(wd & 0xFFFFFFu) * 16 + d4l];
        }
    }
    for (int r = 0; r < nr; ++r) {
        uint32 wd2 = 0; uint2 v2 = make_uint2(0u, 0u);
        int idx2 = s0 + (r + 1) * 4 + q;
        if (idx2 < e0) {
            wd2 = sES[idx2];
            v2 = Ts2[(size_t)(wd2 & 0xFFFFFFu) * 16 + d4l];
        }
#pragma unroll
        for (int k = 0; k < 4; ++k) {
            int srcl = 16 * k + rsl;
            uint32 gx = (uint32)__shfl((int)v.x, srcl);
            uint32 gy = (uint32)__shfl((int)v.y, srcl);
            uint32 g = selY ? gy : gx;
            float val = selH ? bfhi(g) : bflo(g);
            uint32 wk = (uint32)__shfl((int)wd, 16 * k);
            int sd4 = __builtin_amdgcn_readfirstlane((int)((wk >> 24) & 15u));
            ACC_ADD(sd4, val);
        }
        wd = wd2; v = v2;
    }

    // epilogue: wave w finishes its 16 dests; lane l handles dim l
#pragma unroll
    for (int j = 0; j < 16; ++j) {
        int node = b * NB + w * 16 + j;
        if (node < n) {
            float dc = dinv[node];
            float rv = __uint_as_float(((uint32)RsU[(size_t)node * 64 + lane]) << 16);
            float h = fmaxf(fmaf(dc, a[j], rv), 0.0f);
            HbU[(size_t)node * 64 + lane] = (unsigned short)bf16rn(h);
        }
    }
}

// ---------------- mean-pool over sorted batch (bf16x2 loads, half-wave/node) ----------------
__global__ __launch_bounds__(256) void pool_kernel(
    const uint32* __restrict__ Hb, const int* __restrict__ batch,
    float* __restrict__ pooled, float* __restrict__ cnt, int n) {
    __shared__ float sAcc[64 * 64];
    __shared__ float sCnt[64];
    int tid = threadIdx.x;
    for (int i = tid; i < 4096; i += 256) sAcc[i] = 0.0f;
    if (tid < 64) sCnt[tid] = 0.0f;
    __syncthreads();

    int w = tid >> 6, lane = tid & 63;
    int half = lane >> 5, d2 = lane & 31;
    int s = blockIdx.x * 256 + w * 64;
    int e = min(s + 64, n);
    float a0 = 0.0f, a1 = 0.0f, c = 0.0f;
    int gcur = -1;
    for (int i = s + half; i < e; i += 2) {
        int g = batch[i];
        if (g != gcur) {
            if (gcur >= 0) {
                atomicAdd(&sAcc[gcur * 64 + 2 * d2], a0);
                atomicAdd(&sAcc[gcur * 64 + 2 * d2 + 1], a1);
                if (d2 == 0) atomicAdd(&sCnt[gcur], c);
            }
            gcur = g; a0 = 0.0f; a1 = 0.0f; c = 0.0f;
        }
        uint32 u = Hb[(size_t)i * 32 + d2];
        a0 += bflo(u);
        a1 += bfhi(u);
        c += 1.0f;
    }
    if (gcur >= 0) {
        atomicAdd(&sAcc[gcur * 64 + 2 * d2], a0);
        atomicAdd(&sAcc[gcur * 64 + 2 * d2 + 1], a1);
        if (d2 == 0) atomicAdd(&sCnt[gcur], c);
    }
    __syncthreads();
    for (int i = tid; i < 4096; i += 256) {
        float v = sAcc[i];
        if (v != 0.0f) atomicAdd(&pooled[i], v);
    }
    if (tid < 64) {
        float v = sCnt[tid];
        if (v != 0.0f) atomicAdd(&cnt[tid], v);
    }
}

// ---------------- out[g,o] = (pooled[g,:]/max(cnt,1)) @ fcw + fcb ----------------
__global__ void final_fc(const float* __restrict__ pooled, const float* __restrict__ cnt,
                         const float* __restrict__ fcw, const float* __restrict__ fcb,
                         float* __restrict__ out) {
    int idx = blockIdx.x * 256 + threadIdx.x;
    if (idx >= 64 * 32) return;
    int g = idx >> 5, o = idx & 31;
    float c = fmaxf(cnt[g], 1.0f);
    float acc = 0.0f;
#pragma unroll
    for (int k = 0; k < 64; ++k) acc = fmaf(pooled[g * 64 + k], fcw[k * 32 + o], acc);
    out[idx] = acc / c + fcb[o];
}

extern "C" void kernel_launch(void* const* d_in, const int* in_sizes, int n_in,
                              void* d_out, int out_size, void* d_ws, size_t ws_size,
                              hipStream_t stream) {
    const float* x       = (const float*)d_in[0];
    const int*   eidx    = (const int*)d_in[1];
    const int*   batch   = (const int*)d_in[2];
    const float* w1_init = (const float*)d_in[3];
    const float* w1_root = (const float*)d_in[4];
    const float* b1      = (const float*)d_in[5];
    const float* w2_init = (const float*)d_in[6];
    const float* w2_root = (const float*)d_in[7];
    const float* b2      = (const float*)d_in[8];
    const float* fc_w    = (const float*)d_in[9];
    const float* fc_b    = (const float*)d_in[10];
    float* out = (float*)d_out;

    const int N = in_sizes[0] / 64;
    const int E = in_sizes[1] / 2;
    const int* row = eidx;
    const int* col = eidx + E;

    const int B = (N + NB - 1) / NB;  // 391 buckets

    // workspace: bpack(B*CAP) | es(B*CAP) | bcnt(MAXB) | pooled(4096) | cnt(64)
    // | obnd(B*17) | dinv(N) | wt(16384 uints) | Ts(N*32) | Rs(N*32) | Hb(N*32)
    uint32* bpack = (uint32*)d_ws;
    uint32* es    = bpack + (size_t)B * CAP;
    int*   bcnt   = (int*)(es + (size_t)B * CAP);
    float* pooled = (float*)(bcnt + MAXB);
    float* cnt    = pooled + 64 * 64;
    int*   obnd   = (int*)(cnt + 64);
    float* dinv   = (float*)(obnd + (size_t)B * 17 + 3);  // pad to 16B-ish
    uint32* wtU   = (uint32*)(dinv + N);
    uint32* Ts    = wtU + 16384;
    uint32* Rs    = Ts + (size_t)N * 32;
    uint32* Hb    = Rs + (size_t)N * 32;
    ushort16* wt  = (ushort16*)wtU;

    hipMemsetAsync(bcnt, 0, (size_t)(MAXB + 64 * 64 + 64) * sizeof(int), stream);

    const int EB = (E + P1_CHUNK - 1) / P1_CHUNK;
    bucket_kernel<<<128 + EB, 256, 0, stream>>>(row, col, bpack, bcnt, E,
                                                w1_init, w1_root, w2_init, w2_root, wt);
    sort_kernel<<<B, 1024, 0, stream>>>(bpack, bcnt, es, obnd, dinv, N);

    // layer 1
    gemm_mfma<<<(N + 63) / 64, 256, 0, stream>>>(x, wt, b1, dinv,
                                                 (ushort16*)Ts, (ushort16*)Rs, N, 1);
    push_gather<<<B, 1024, 0, stream>>>((const uint2*)Ts, (const unsigned short*)Rs,
                                        es, bcnt, obnd, dinv, (unsigned short*)Hb, N);

    // layer 2
    gemm_mfma<<<(N + 63) / 64, 256, 0, stream>>>(Hb, wt + (size_t)4 * 4096, b2, dinv,
                                                 (ushort16*)Ts, (ushort16*)Rs, N, 0);
    push_gather<<<B, 1024, 0, stream>>>((const uint2*)Ts, (const unsigned short*)Rs,
                                        es, bcnt, obnd, dinv, (unsigned short*)Hb, N);

    // pool + FC
    pool_kernel<<<(N + 255) / 256, 256, 0, stream>>>(Hb, batch, pooled, cnt, N);
    final_fc<<<(64 * 32 + 255) / 256, 256, 0, stream>>>(pooled, cnt, fc_w, fc_b, out);
}